// Round 2
// baseline (914.541 us; speedup 1.0000x reference)
//
#include <hip/hip_runtime.h>

// Sparse conv via on-device counting-sort (CSR by out_row) + gather compute.
// N=262144 voxels, M=131072 pairs/offset (2^17), K=27, C_in=C_out=32, fp32 in/out.
// Hot path has ZERO float atomics: contributions are gathered per output row.

constexpr int N_VOX   = 262144;
constexpr int M_PAIRS = 131072;          // 2^17
constexpr int K_VOL   = 27;
constexpr int C       = 32;
constexpr int E_TOT   = K_VOL * M_PAIRS; // 3538944

typedef _Float16 h2 __attribute__((ext_vector_type(2)));

// ---- workspace layout (bytes) ----
constexpr size_t WS_CNT     = 0;                    // int[N]   : 1 MB
constexpr size_t WS_OFFS    = (size_t)1 << 20;      // int[N]   : 1 MB
constexpr size_t WS_CUR     = (size_t)2 << 20;      // int[N]   : 1 MB
constexpr size_t WS_BSUM    = (size_t)3 << 20;      // int[256]
constexpr size_t WS_BSCAN   = ((size_t)3 << 20) + 4096;
constexpr size_t WS_ENTRIES = (size_t)4 << 20;      // int[E]   : 13.5 MB
constexpr size_t WS_HIN     = (size_t)20 << 20;     // ushort[N*32] : 16 MB
// total 36 MB

__device__ inline float fdot2f(unsigned a, unsigned b, float c) {
#if __has_builtin(__builtin_amdgcn_fdot2)
    return __builtin_amdgcn_fdot2(__builtin_bit_cast(h2, a),
                                  __builtin_bit_cast(h2, b), c, false);
#else
    h2 x = __builtin_bit_cast(h2, a), y = __builtin_bit_cast(h2, b);
    return fmaf((float)x[0], (float)y[0], fmaf((float)x[1], (float)y[1], c));
#endif
}

// Phase 0: input f32 -> f16, zero histogram counters.
__global__ __launch_bounds__(256) void init_convert(const float* __restrict__ in,
                                                    unsigned short* __restrict__ hin,
                                                    int* __restrict__ cnt) {
    const int idx = blockIdx.x * 256 + threadIdx.x;
    const int stride = gridDim.x * 256;
    for (int i = idx; i < N_VOX * C; i += stride) {
        hin[i] = __builtin_bit_cast(unsigned short, (_Float16)in[i]);
    }
    for (int i = idx; i < N_VOX; i += stride) cnt[i] = 0;
}

// Phase 1: histogram of out_map.
__global__ __launch_bounds__(256) void hist_kernel(const int* __restrict__ out_map,
                                                   int* __restrict__ cnt) {
    const int idx = blockIdx.x * 256 + threadIdx.x;
    const int stride = gridDim.x * 256;
    for (int e = idx; e < E_TOT; e += stride) {
        atomicAdd(&cnt[out_map[e]], 1);
    }
}

// Phase 2a: per-block (1024 elems) exclusive scan; block totals to bsum.
__global__ __launch_bounds__(256) void scan1(const int* __restrict__ cnt,
                                             int* __restrict__ offs,
                                             int* __restrict__ bsum) {
    const int t = threadIdx.x;
    const int base = blockIdx.x * 1024 + t * 4;
    int4 v = *(const int4*)(cnt + base);
    const int s4 = v.x + v.y + v.z + v.w;
    const int lane = t & 63;
    int inc = s4;
    #pragma unroll
    for (int off = 1; off < 64; off <<= 1) {
        int u = __shfl_up(inc, off);
        if (lane >= off) inc += u;
    }
    __shared__ int wsum[4];
    const int w = t >> 6;
    if (lane == 63) wsum[w] = inc;
    __syncthreads();
    int woff = 0;
    for (int i = 0; i < w; ++i) woff += wsum[i];
    const int excl = woff + inc - s4;
    int4 o;
    o.x = excl; o.y = excl + v.x; o.z = excl + v.x + v.y; o.w = excl + v.x + v.y + v.z;
    *(int4*)(offs + base) = o;
    if (t == 255) bsum[blockIdx.x] = woff + inc;
}

// Phase 2b: scan the 256 block sums (single wave).
__global__ __launch_bounds__(64) void scan2(const int* __restrict__ bsum,
                                            int* __restrict__ bscan) {
    const int t = threadIdx.x;  // 0..63
    int4 v = ((const int4*)bsum)[t];
    const int s4 = v.x + v.y + v.z + v.w;
    int inc = s4;
    #pragma unroll
    for (int off = 1; off < 64; off <<= 1) {
        int u = __shfl_up(inc, off);
        if (t >= off) inc += u;
    }
    const int excl = inc - s4;
    int4 o;
    o.x = excl; o.y = excl + v.x; o.z = excl + v.x + v.y; o.w = excl + v.x + v.y + v.z;
    ((int4*)bscan)[t] = o;
}

// Phase 2c: add block offsets; cur = offs (fill cursors).
__global__ __launch_bounds__(256) void scan3(int* __restrict__ offs,
                                             const int* __restrict__ bscan,
                                             int* __restrict__ cur) {
    const int i = blockIdx.x * 1024 + threadIdx.x * 4;
    const int add = bscan[blockIdx.x];
    int4 v = *(const int4*)(offs + i);
    v.x += add; v.y += add; v.z += add; v.w += add;
    *(int4*)(offs + i) = v;
    *(int4*)(cur + i) = v;
}

// Phase 3: fill entry list. entry = (k<<18) | in_row  (k<27 -> 5 bits, in<2^18).
__global__ __launch_bounds__(256) void fill_kernel(const int* __restrict__ in_map,
                                                   const int* __restrict__ out_map,
                                                   int* __restrict__ cur,
                                                   int* __restrict__ entries) {
    const int idx = blockIdx.x * 256 + threadIdx.x;
    const int stride = gridDim.x * 256;
    for (int e = idx; e < E_TOT; e += stride) {
        const int r = out_map[e];
        const int p = ((e >> 17) << 18) | in_map[e];
        const int pos = atomicAdd(&cur[r], 1);
        entries[pos] = p;
    }
}

// Phase 4: per-row gather compute. One 32-lane group per output row.
// Kernel weights f16 in LDS as uint2 L[k][jj][c] = (half2(K[4jj],K[4jj+1]), half2(K[4jj+2],K[4jj+3])) col c.
__global__ __launch_bounds__(512) void compute_kernel(
    const unsigned short* __restrict__ hin,
    const float* __restrict__ kern,
    const float* __restrict__ bias,
    const int*  __restrict__ offs,
    const int*  __restrict__ entries,
    float* __restrict__ out)
{
    __shared__ uint2 KL[K_VOL * 8 * 32];  // 6912 * 8B = 55296 B

    for (int u = threadIdx.x; u < K_VOL * 8 * 32; u += 512) {
        const int k  = u >> 8;
        const int jj = (u >> 5) & 7;
        const int cc = u & 31;
        const float* kb = kern + k * 1024 + cc;
        h2 p0, p1;
        p0[0] = (_Float16)kb[(4 * jj + 0) * 32];
        p0[1] = (_Float16)kb[(4 * jj + 1) * 32];
        p1[0] = (_Float16)kb[(4 * jj + 2) * 32];
        p1[1] = (_Float16)kb[(4 * jj + 3) * 32];
        uint2 val;
        val.x = __builtin_bit_cast(unsigned, p0);
        val.y = __builtin_bit_cast(unsigned, p1);
        KL[u] = val;
    }
    __syncthreads();

    const int group = threadIdx.x >> 5;   // 0..15
    const int c     = threadIdx.x & 31;
    const float bval = bias[c];

    for (int r = blockIdx.x * 16 + group; r < N_VOX; r += gridDim.x * 16) {
        const int s     = offs[r];
        const int e_end = (r + 1 < N_VOX) ? offs[r + 1] : E_TOT;
        const int n     = e_end - s;
        float acc0 = 0.f, acc1 = 0.f;

        if (n > 0) {
            const int* ep = entries + s;
            int p  = ep[0];
            int kk = p >> 18;
            uint4 qa[4];
            {
                const uint4* row = (const uint4*)(hin + (size_t)(p & 0x3FFFF) * 32);
                #pragma unroll
                for (int t = 0; t < 4; ++t) qa[t] = row[t];
            }
            for (int i = 1; i < n; ++i) {
                const int pn = ep[i];
                const int kn = pn >> 18;
                uint4 qb[4];
                {
                    const uint4* row = (const uint4*)(hin + (size_t)(pn & 0x3FFFF) * 32);
                    #pragma unroll
                    for (int t = 0; t < 4; ++t) qb[t] = row[t];
                }
                const uint2* kl = KL + kk * 256 + c;
                #pragma unroll
                for (int t = 0; t < 4; ++t) {
                    const uint2 kA = kl[(2 * t + 0) * 32];
                    const uint2 kB = kl[(2 * t + 1) * 32];
                    acc0 = fdot2f(qa[t].x, kA.x, acc0);
                    acc1 = fdot2f(qa[t].y, kA.y, acc1);
                    acc0 = fdot2f(qa[t].z, kB.x, acc0);
                    acc1 = fdot2f(qa[t].w, kB.y, acc1);
                }
                #pragma unroll
                for (int t = 0; t < 4; ++t) qa[t] = qb[t];
                kk = kn;
            }
            const uint2* kl = KL + kk * 256 + c;
            #pragma unroll
            for (int t = 0; t < 4; ++t) {
                const uint2 kA = kl[(2 * t + 0) * 32];
                const uint2 kB = kl[(2 * t + 1) * 32];
                acc0 = fdot2f(qa[t].x, kA.x, acc0);
                acc1 = fdot2f(qa[t].y, kA.y, acc1);
                acc0 = fdot2f(qa[t].z, kB.x, acc0);
                acc1 = fdot2f(qa[t].w, kB.y, acc1);
            }
        }
        out[(size_t)r * 32 + c] = acc0 + acc1 + bval;
    }
}

extern "C" void kernel_launch(void* const* d_in, const int* in_sizes, int n_in,
                              void* d_out, int out_size, void* d_ws, size_t ws_size,
                              hipStream_t stream) {
    const float* input   = (const float*)d_in[0];
    const float* kernel  = (const float*)d_in[1];
    const float* bias    = (const float*)d_in[2];
    const int*   in_map  = (const int*)d_in[3];
    const int*   out_map = (const int*)d_in[4];
    float* out = (float*)d_out;

    char* ws = (char*)d_ws;
    int* cnt            = (int*)(ws + WS_CNT);
    int* offs           = (int*)(ws + WS_OFFS);
    int* cur            = (int*)(ws + WS_CUR);
    int* bsum           = (int*)(ws + WS_BSUM);
    int* bscan          = (int*)(ws + WS_BSCAN);
    int* entries        = (int*)(ws + WS_ENTRIES);
    unsigned short* hin = (unsigned short*)(ws + WS_HIN);

    init_convert<<<2048, 256, 0, stream>>>(input, hin, cnt);
    hist_kernel <<<2048, 256, 0, stream>>>(out_map, cnt);
    scan1       <<<256,  256, 0, stream>>>(cnt, offs, bsum);
    scan2       <<<1,     64, 0, stream>>>(bsum, bscan);
    scan3       <<<256,  256, 0, stream>>>(offs, bscan, cur);
    fill_kernel <<<2048, 256, 0, stream>>>(in_map, out_map, cur, entries);
    compute_kernel<<<2048, 512, 0, stream>>>(hin, kernel, bias, offs, entries, out);
}

// Round 3
// 720.433 us; speedup vs baseline: 1.2694x; 1.2694x over previous
//
#include <hip/hip_runtime.h>

// Sparse conv: out[r] = bias + sum_{(k,m): out_map[k,m]==r} input[in_map[k,m]] @ W_k
// N=262144, M=131072, K=27, C_in=C_out=32. fp32 in/out, f16 internal (fdot2).
//
// Pipeline (4 launches):
//   0. hipMemsetAsync cnt=0
//   1. convert: input f32 -> f16 rows (64B/row)
//   2. fill:    direct bucket scatter: pos=atomicAdd(cnt[r]); slots[r*CAP+pos]=(k<<18)|in_row
//   3. compute: per output row: one coalesced load of its entry list, shfl-broadcast
//               entries, software-pipelined 64B row gathers + f16 dot2 MACs, one store.

constexpr int N_VOX   = 262144;
constexpr int M_PAIRS = 131072;          // 2^17
constexpr int K_VOL   = 27;
constexpr int C       = 32;
constexpr int E_TOT   = K_VOL * M_PAIRS; // 3538944
constexpr int CAP     = 44;              // max entries/row (Poisson(13.5); P(overflow)~7e-6)
constexpr int RM      = 0x3FFFF;         // in_row mask (18 bits)

typedef _Float16 h2 __attribute__((ext_vector_type(2)));

// ---- workspace layout ----
constexpr size_t WS_CNT   = 0;                       // int[N]        : 1 MB
constexpr size_t WS_HIN   = (size_t)1 << 20;         // ushort[N*32]  : 16 MB
constexpr size_t WS_SLOTS = (size_t)17 << 20;        // int[N*CAP]    : 46.1 MB
// total ~63.1 MB

__device__ inline float fdot2f(unsigned a, unsigned b, float c) {
#if __has_builtin(__builtin_amdgcn_fdot2)
    return __builtin_amdgcn_fdot2(__builtin_bit_cast(h2, a),
                                  __builtin_bit_cast(h2, b), c, false);
#else
    h2 x = __builtin_bit_cast(h2, a), y = __builtin_bit_cast(h2, b);
    return fmaf((float)x[0], (float)y[0], fmaf((float)x[1], (float)y[1], c));
#endif
}

// Phase 1: input f32 -> f16. 8 floats/thread, exact grid (4096x256).
__global__ __launch_bounds__(256) void convert_kernel(const float* __restrict__ in,
                                                      uint4* __restrict__ hin4) {
    const int idx = blockIdx.x * 256 + threadIdx.x;   // 0 .. 2^20-1
    const float4* in4 = (const float4*)in;
    const float4 a = in4[2 * idx];
    const float4 b = in4[2 * idx + 1];
    h2 p0; p0[0] = (_Float16)a.x; p0[1] = (_Float16)a.y;
    h2 p1; p1[0] = (_Float16)a.z; p1[1] = (_Float16)a.w;
    h2 p2; p2[0] = (_Float16)b.x; p2[1] = (_Float16)b.y;
    h2 p3; p3[0] = (_Float16)b.z; p3[1] = (_Float16)b.w;
    uint4 v;
    v.x = __builtin_bit_cast(unsigned, p0);
    v.y = __builtin_bit_cast(unsigned, p1);
    v.z = __builtin_bit_cast(unsigned, p2);
    v.w = __builtin_bit_cast(unsigned, p3);
    hin4[idx] = v;
}

// Phase 2: bucket fill. 4 entries/thread, exact grid (3456x256).
__global__ __launch_bounds__(256) void fill_kernel(const int* __restrict__ in_map,
                                                   const int* __restrict__ out_map,
                                                   int* __restrict__ cnt,
                                                   int* __restrict__ slots) {
    const int e4 = blockIdx.x * 256 + threadIdx.x;    // 0 .. E/4-1
    const int4 iv = ((const int4*)in_map)[e4];
    const int4 ov = ((const int4*)out_map)[e4];
    const int ebase = e4 * 4;
    {
        const int p = (((ebase + 0) >> 17) << 18) | iv.x;
        const int pos = atomicAdd(&cnt[ov.x], 1);
        if (pos < CAP) slots[ov.x * CAP + pos] = p;
    }
    {
        const int p = (((ebase + 1) >> 17) << 18) | iv.y;
        const int pos = atomicAdd(&cnt[ov.y], 1);
        if (pos < CAP) slots[ov.y * CAP + pos] = p;
    }
    {
        const int p = (((ebase + 2) >> 17) << 18) | iv.z;
        const int pos = atomicAdd(&cnt[ov.z], 1);
        if (pos < CAP) slots[ov.z * CAP + pos] = p;
    }
    {
        const int p = (((ebase + 3) >> 17) << 18) | iv.w;
        const int pos = atomicAdd(&cnt[ov.w], 1);
        if (pos < CAP) slots[ov.w * CAP + pos] = p;
    }
}

// Phase 3: compute. 512 threads = 16 groups of 32 lanes; one output row per group.
__global__ __launch_bounds__(512) void compute_kernel(
    const unsigned short* __restrict__ hin,
    const float* __restrict__ kern,
    const float* __restrict__ bias,
    const int*  __restrict__ cnt,
    const int*  __restrict__ slots,
    float* __restrict__ out)
{
    __shared__ uint2 KL[K_VOL * 8 * 32];  // f16 weights, 55296 B

    for (int u = threadIdx.x; u < K_VOL * 8 * 32; u += 512) {
        const int k  = u >> 8;
        const int jj = (u >> 5) & 7;
        const int cc = u & 31;
        const float* kb = kern + k * 1024 + cc;
        h2 p0, p1;
        p0[0] = (_Float16)kb[(4 * jj + 0) * 32];
        p0[1] = (_Float16)kb[(4 * jj + 1) * 32];
        p1[0] = (_Float16)kb[(4 * jj + 2) * 32];
        p1[1] = (_Float16)kb[(4 * jj + 3) * 32];
        uint2 val;
        val.x = __builtin_bit_cast(unsigned, p0);
        val.y = __builtin_bit_cast(unsigned, p1);
        KL[u] = val;
    }
    __syncthreads();

    const int group = threadIdx.x >> 5;   // 0..15
    const int c     = threadIdx.x & 31;
    const int gbase = threadIdx.x & 32;   // group base within the wave
    const float bval = bias[c];

#define ENT(j) (((j) < 32) ? __shfl(e_lo, gbase + (j), 64) \
                           : __shfl(e_hi, gbase + (j) - 32, 64))

#define DOT2(P, Q0, Q1, Q2, Q3)                                   \
    {                                                             \
        const uint2* kl = KL + ((P) >> 18) * 256 + c;             \
        const uint2 kA0 = kl[0 * 32], kB0 = kl[1 * 32];           \
        acc0 = fdot2f((Q0).x, kA0.x, acc0);                       \
        acc1 = fdot2f((Q0).y, kA0.y, acc1);                       \
        acc0 = fdot2f((Q0).z, kB0.x, acc0);                       \
        acc1 = fdot2f((Q0).w, kB0.y, acc1);                       \
        const uint2 kA1 = kl[2 * 32], kB1 = kl[3 * 32];           \
        acc0 = fdot2f((Q1).x, kA1.x, acc0);                       \
        acc1 = fdot2f((Q1).y, kA1.y, acc1);                       \
        acc0 = fdot2f((Q1).z, kB1.x, acc0);                       \
        acc1 = fdot2f((Q1).w, kB1.y, acc1);                       \
        const uint2 kA2 = kl[4 * 32], kB2 = kl[5 * 32];           \
        acc0 = fdot2f((Q2).x, kA2.x, acc0);                       \
        acc1 = fdot2f((Q2).y, kA2.y, acc1);                       \
        acc0 = fdot2f((Q2).z, kB2.x, acc0);                       \
        acc1 = fdot2f((Q2).w, kB2.y, acc1);                       \
        const uint2 kA3 = kl[6 * 32], kB3 = kl[7 * 32];           \
        acc0 = fdot2f((Q3).x, kA3.x, acc0);                       \
        acc1 = fdot2f((Q3).y, kA3.y, acc1);                       \
        acc0 = fdot2f((Q3).z, kB3.x, acc0);                       \
        acc1 = fdot2f((Q3).w, kB3.y, acc1);                       \
    }

#define LOADROW(P, Q0, Q1, Q2, Q3)                                          \
    {                                                                       \
        const uint4* row = (const uint4*)(hin + (size_t)((P) & RM) * 32);   \
        Q0 = row[0]; Q1 = row[1]; Q2 = row[2]; Q3 = row[3];                 \
    }

    for (int r = blockIdx.x * 16 + group; r < N_VOX; r += gridDim.x * 16) {
        int n = cnt[r];
        n = (n < CAP) ? n : CAP;
        const int sbase = r * CAP;
        // One coalesced read of the whole entry list (lanes beyond n: garbage, unused).
        const int e_lo = slots[sbase + c];
        const int e_hi = (c < CAP - 32) ? slots[sbase + 32 + c] : 0;

        float acc0 = 0.f, acc1 = 0.f;
        uint4 qa0, qa1, qa2, qa3, qb0, qb1, qb2, qb3;
        int pa = 0, pb = 0;

        if (n > 0) { pa = ENT(0); LOADROW(pa, qa0, qa1, qa2, qa3); }
        if (n > 1) { pb = ENT(1); LOADROW(pb, qb0, qb1, qb2, qb3); }

        int i = 0;
        for (; i + 1 < n; i += 2) {
            const int pn0 = ENT(i + 2);   // garbage if i+2 >= n (discarded)
            const int pn1 = ENT(i + 3);
            DOT2(pa, qa0, qa1, qa2, qa3);
            if (i + 2 < n) { pa = pn0; LOADROW(pa, qa0, qa1, qa2, qa3); }
            DOT2(pb, qb0, qb1, qb2, qb3);
            if (i + 3 < n) { pb = pn1; LOADROW(pb, qb0, qb1, qb2, qb3); }
        }
        if (i < n) { DOT2(pa, qa0, qa1, qa2, qa3); }

        out[(size_t)r * 32 + c] = acc0 + acc1 + bval;
    }
#undef ENT
#undef DOT2
#undef LOADROW
}

extern "C" void kernel_launch(void* const* d_in, const int* in_sizes, int n_in,
                              void* d_out, int out_size, void* d_ws, size_t ws_size,
                              hipStream_t stream) {
    const float* input   = (const float*)d_in[0];
    const float* kernel  = (const float*)d_in[1];
    const float* bias    = (const float*)d_in[2];
    const int*   in_map  = (const int*)d_in[3];
    const int*   out_map = (const int*)d_in[4];
    float* out = (float*)d_out;

    char* ws = (char*)d_ws;
    int* cnt            = (int*)(ws + WS_CNT);
    unsigned short* hin = (unsigned short*)(ws + WS_HIN);
    int* slots          = (int*)(ws + WS_SLOTS);

    hipMemsetAsync(cnt, 0, N_VOX * sizeof(int), stream);
    convert_kernel<<<4096, 256, 0, stream>>>(input, (uint4*)hin);
    fill_kernel   <<<E_TOT / 4 / 256, 256, 0, stream>>>(in_map, out_map, cnt, slots);
    compute_kernel<<<2048, 512, 0, stream>>>(hin, kernel, bias, cnt, slots, out);
}